// Round 6
// baseline (168.368 us; speedup 1.0000x reference)
//
#include <hip/hip_runtime.h>

// Problem constants (PARTViT pairwise head)
#define BB 64
#define NN 576
#define DD 768
#define KK 1024
#define ROWS (BB * NN)    // 36864 patch rows
#define PAIRS (BB * KK)   // 65536 pairs
// d_out layout: [PAIRS*2] f32 head output, then [PAIRS*2] f32 echoed indices
//
// R9 = R8 with one fix: LOAD ORDER. R8 issued z-loads then W-loads; vmcnt
// is ordered, so the first FMA (needs W = youngest loads) forced vmcnt(0)
// and drained the entire 12 KB z prefetch before any compute - the designed
// overlap never happened (R8 gained only ~3 us). Now W-loads go FIRST,
// pinned with a single sched_barrier(0) between the groups, giving the
// ladder: rowdot0 @ vmcnt(9) -> rowdot1 @ vmcnt(6) -> bfly/store (overlaps
// rows 2-3 in flight) -> rowdot2 @ vmcnt(3) -> rowdot3 @ vmcnt(0).
// Live VGPR ~ 48 W + 48 v + 8 acc ~ 110 < 128 cap at 4 waves/SIMD.
// Layout note: full-wave-per-row is REQUIRED - weight residency scales
// inversely with lanes/row (64-lane: 24 float2; 16-lane: 96 float2 = 192
// VGPR, impossible). Shorter-butterfly layouts die on register arithmetic.
// K2 verbatim from R0 (proven, L2-resident gathers).

#define K1_BLOCKS 2304   // ROWS / (4 waves * 4 rows)
#define TPB 256

// Per-patch projection table: P[r] = { z[r]·W[:768,0], z[r]·W[:768,1],
//                                      z[r]·W[768:,0], z[r]·W[768:,1] }
// Static device global (576 KB); fully rewritten each launch (replay-safe).
__device__ float4 g_P[ROWS];

__device__ __forceinline__ float4 rowdot(const float4 v[3],
                                         const float2 wa[3][4],
                                         const float2 wb[3][4]) {
    float s0 = 0.f, s1 = 0.f, s2 = 0.f, s3 = 0.f;
#pragma unroll
    for (int j = 0; j < 3; ++j) {
        const float e0 = v[j].x, e1 = v[j].y, e2 = v[j].z, e3 = v[j].w;
        s0 = fmaf(e0, wa[j][0].x, s0);
        s0 = fmaf(e1, wa[j][1].x, s0);
        s0 = fmaf(e2, wa[j][2].x, s0);
        s0 = fmaf(e3, wa[j][3].x, s0);
        s1 = fmaf(e0, wa[j][0].y, s1);
        s1 = fmaf(e1, wa[j][1].y, s1);
        s1 = fmaf(e2, wa[j][2].y, s1);
        s1 = fmaf(e3, wa[j][3].y, s1);
        s2 = fmaf(e0, wb[j][0].x, s2);
        s2 = fmaf(e1, wb[j][1].x, s2);
        s2 = fmaf(e2, wb[j][2].x, s2);
        s2 = fmaf(e3, wb[j][3].x, s2);
        s3 = fmaf(e0, wb[j][0].y, s3);
        s3 = fmaf(e1, wb[j][1].y, s3);
        s3 = fmaf(e2, wb[j][2].y, s3);
        s3 = fmaf(e3, wb[j][3].y, s3);
    }
    return make_float4(s0, s1, s2, s3);
}

// Interleaved dual butterfly: 8 independent add chains, 6 steps.
__device__ __forceinline__ void bfly2(float4& p, float4& q) {
#pragma unroll
    for (int off = 32; off > 0; off >>= 1) {
        p.x += __shfl_xor(p.x, off, 64);
        q.x += __shfl_xor(q.x, off, 64);
        p.y += __shfl_xor(p.y, off, 64);
        q.y += __shfl_xor(q.y, off, 64);
        p.z += __shfl_xor(p.z, off, 64);
        q.z += __shfl_xor(q.z, off, 64);
        p.w += __shfl_xor(p.w, off, 64);
        q.w += __shfl_xor(q.w, off, 64);
    }
}

// Kernel 1: 4 rows per wave, straight-line, W-loads first then z-loads.
__global__ __launch_bounds__(TPB, 4)
void partvit_proj(const float* __restrict__ z, const float* __restrict__ W) {
    const int lane = threadIdx.x & 63;
    const int wave = threadIdx.x >> 6;   // 0..3

    // This wave's 4 contiguous rows. 2304 blocks * 4 waves * 4 rows = 36864.
    const int rbase = (blockIdx.x * 4 + wave) * 4;

    // ---- W loads FIRST. W is [1536,2] row-major: W[d,t] at 2*d+t -> float2
    // per d. Lane l owns d = j*256 + 4l + c (j=0..2, c=0..3) of each half.
    // Oldest in the vmcnt queue -> retiring them does not drain the z
    // prefetch behind them.
    const float2* __restrict__ W2 = (const float2*)W;
    float2 wa[3][4], wb[3][4];
#pragma unroll
    for (int j = 0; j < 3; ++j)
#pragma unroll
        for (int c = 0; c < 4; ++c) {
            const int d = j * 256 + (lane << 2) + c;
            wa[j][c] = W2[d];        // first-half weights (patch-0 slot)
            wb[j][c] = W2[d + DD];   // second-half weights (patch-1 slot)
        }

    // Pin group order: nothing (esp. the z-loads) may be scheduled above
    // this point, so W stays oldest in the vmcnt queue. One barrier between
    // load groups only - not per-instruction pinning.
    __builtin_amdgcn_sched_barrier(0);

    // ---- 12 z row-loads (12 KB per wave) ----
    const float4* __restrict__ z4 = (const float4*)z;  // 192 float4 per row
    float4 v[4][3];
#pragma unroll
    for (int rr = 0; rr < 4; ++rr)
#pragma unroll
        for (int j = 0; j < 3; ++j)
            v[rr][j] = z4[(size_t)(rbase + rr) * 192 + j * 64 + lane];

    // vmcnt ladder: rowdot0 waits vmcnt(9) (9 KB still in flight), rowdot1
    // vmcnt(6); bfly+store have no vm dependency and overlap rows 2-3
    // loads; rowdot2 vmcnt(3); rowdot3 vmcnt(0).
    float4 p0 = rowdot(v[0], wa, wb);
    float4 p1 = rowdot(v[1], wa, wb);
    bfly2(p0, p1);
    if (lane == 0)      g_P[rbase + 0] = p0;
    else if (lane == 1) g_P[rbase + 1] = p1;

    float4 p2 = rowdot(v[2], wa, wb);
    float4 p3 = rowdot(v[3], wa, wb);
    bfly2(p2, p3);
    if (lane == 0)      g_P[rbase + 2] = p2;
    else if (lane == 1) g_P[rbase + 3] = p3;
}

// Kernel 2 (verbatim R0): out = P[i0].xy + P[i1].zw + bias ; echo indices.
// Indices clamped to [0, NN-1] so a dtype-contract surprise yields a clean
// absmax failure instead of a memory fault.
__global__ __launch_bounds__(TPB) void partvit_pairs(const int* __restrict__ idx,
                                                     const float* __restrict__ bh,
                                                     float* __restrict__ out) {
    const int t = blockIdx.x * blockDim.x + threadIdx.x;  // pair id = b*K + k
    if (t >= PAIRS) return;
    const int2 id = ((const int2*)idx)[t];
    const int i0 = min(max(id.x, 0), NN - 1);
    const int i1 = min(max(id.y, 0), NN - 1);
    const int b = t >> 10;  // K = 1024
    const float4 p0 = g_P[b * NN + i0];
    const float4 p1 = g_P[b * NN + i1];
    const float b0 = bh[0], b1 = bh[1];
    ((float2*)out)[t] = make_float2(p0.x + p1.z + b0, p0.y + p1.w + b1);
    ((float2*)out)[PAIRS + t] = make_float2((float)id.x, (float)id.y);
}

extern "C" void kernel_launch(void* const* d_in, const int* in_sizes, int n_in,
                              void* d_out, int out_size, void* d_ws, size_t ws_size,
                              hipStream_t stream) {
    const float* z   = (const float*)d_in[0];
    const int*   idx = (const int*)d_in[1];
    const float* W   = (const float*)d_in[2];
    const float* bh  = (const float*)d_in[3];
    float*       out = (float*)d_out;
    (void)d_ws; (void)ws_size; (void)in_sizes; (void)n_in; (void)out_size;

    // K1: 2304 blocks * 4 waves, 4 rows/wave, ~9 blocks/CU churn.
    partvit_proj<<<K1_BLOCKS, TPB, 0, stream>>>(z, W);
    // K2: one thread per pair.
    partvit_pairs<<<PAIRS / TPB, TPB, 0, stream>>>(idx, bh, out);
}

// Round 7
// 168.134 us; speedup vs baseline: 1.0014x; 1.0014x over previous
//
#include <hip/hip_runtime.h>

// Problem constants (PARTViT pairwise head)
#define BB 64
#define NN 576
#define DD 768
#define KK 1024
#define ROWS (BB * NN)    // 36864 patch rows
#define PAIRS (BB * KK)   // 65536 pairs
// d_out layout: [PAIRS*2] f32 head output, then [PAIRS*2] f32 echoed indices
//
// R10: occupancy experiment. R8 (deep prefetch) and R9 (issue-order fix)
// were both null -> per-wave MLP is not the limiter. Remaining untested
// axis in the churn structure: RESIDENT WAVES. R8's register-resident
// weight set (~110 VGPR) caps us at 4 waves/SIMD; the fills that hit 6.9
// TB/s run at max occupancy with 8 VGPRs. Outstanding-request capacity
// scales with resident waves. So: stop holding W in registers (it is 12 KB,
// L1-hot after the first block on each CU; VALU and L1 are ~95% idle) and
// reload it inline per FMA group. Live state: 2 rows of z (24 VGPR) + 8
// accumulators + addressing ~= 50 VGPR -> __launch_bounds__(256,8) = 8
// waves/SIMD = 32 waves/CU, 2x R8's concurrency.
//   - 2 rows/wave straight-line, 4608 blocks = 18 blocks/CU churn (churn
//     was the one proven lever: 69 -> ~40 us from R6 -> R8).
//   - W-reload cost: 24 dwordx2/row from L1, ~3.5K instr/CU total - hidden
//     under memory (VALUBusy 4% -> ~10%).
// K2 verbatim from R0 (proven, L2-resident gathers).

#define K1_BLOCKS 4608   // ROWS / (4 waves * 2 rows)
#define TPB 256

// Per-patch projection table: P[r] = { z[r]·W[:768,0], z[r]·W[:768,1],
//                                      z[r]·W[768:,0], z[r]·W[768:,1] }
// Static device global (576 KB); fully rewritten each launch (replay-safe).
__device__ float4 g_P[ROWS];

// Interleaved dual butterfly: 8 independent add chains, 6 steps.
__device__ __forceinline__ void bfly2(float4& p, float4& q) {
#pragma unroll
    for (int off = 32; off > 0; off >>= 1) {
        p.x += __shfl_xor(p.x, off, 64);
        q.x += __shfl_xor(q.x, off, 64);
        p.y += __shfl_xor(p.y, off, 64);
        q.y += __shfl_xor(q.y, off, 64);
        p.z += __shfl_xor(p.z, off, 64);
        q.z += __shfl_xor(q.z, off, 64);
        p.w += __shfl_xor(p.w, off, 64);
        q.w += __shfl_xor(q.w, off, 64);
    }
}

// Kernel 1: 2 rows per wave, straight-line, W re-read from L1 per group.
__global__ __launch_bounds__(TPB, 8)
void partvit_proj(const float* __restrict__ z, const float* __restrict__ W) {
    const int lane = threadIdx.x & 63;
    const int wave = threadIdx.x >> 6;   // 0..3

    // This wave's 2 contiguous rows. 4608 blocks * 4 waves * 2 rows = 36864.
    const int rbase = (blockIdx.x * 4 + wave) * 2;

    // 6 z row-loads (6 KB per wave) issued first.
    const float4* __restrict__ z4 = (const float4*)z;  // 192 float4 per row
    float4 v0[3], v1[3];
#pragma unroll
    for (int j = 0; j < 3; ++j) v0[j] = z4[(size_t)(rbase    ) * 192 + j * 64 + lane];
#pragma unroll
    for (int j = 0; j < 3; ++j) v1[j] = z4[(size_t)(rbase + 1) * 192 + j * 64 + lane];
    const float* f0 = (const float*)v0;  // element e = j*4+c (full unroll ->
    const float* f1 = (const float*)v1;  // promoted to registers)

    // W is [1536,2] row-major: W[d,t] at 2*d+t -> float2 per d. Lane l owns
    // d = j*256 + 4l + c. Loaded INLINE per group (L1-hit, ~12 KB working
    // set) instead of register-cached: that is the whole point of R10 -
    // it is what gets VGPR under 64 so 8 waves/SIMD fit.
    const float2* __restrict__ W2 = (const float2*)W;

    float s00 = 0.f, s01 = 0.f, s02 = 0.f, s03 = 0.f;
    float s10 = 0.f, s11 = 0.f, s12 = 0.f, s13 = 0.f;
#pragma unroll
    for (int j = 0; j < 3; ++j) {
#pragma unroll
        for (int c = 0; c < 4; ++c) {
            const int d = j * 256 + (lane << 2) + c;
            const float2 wA = W2[d];        // first-half weights
            const float2 wB = W2[d + DD];   // second-half weights
            const float e0 = f0[j * 4 + c];
            const float e1 = f1[j * 4 + c];
            s00 = fmaf(e0, wA.x, s00);
            s01 = fmaf(e0, wA.y, s01);
            s02 = fmaf(e0, wB.x, s02);
            s03 = fmaf(e0, wB.y, s03);
            s10 = fmaf(e1, wA.x, s10);
            s11 = fmaf(e1, wA.y, s11);
            s12 = fmaf(e1, wB.x, s12);
            s13 = fmaf(e1, wB.y, s13);
        }
    }

    float4 p0 = make_float4(s00, s01, s02, s03);
    float4 p1 = make_float4(s10, s11, s12, s13);
    bfly2(p0, p1);
    if (lane == 0)      g_P[rbase    ] = p0;
    else if (lane == 1) g_P[rbase + 1] = p1;
}

// Kernel 2 (verbatim R0): out = P[i0].xy + P[i1].zw + bias ; echo indices.
// Indices clamped to [0, NN-1] so a dtype-contract surprise yields a clean
// absmax failure instead of a memory fault.
__global__ __launch_bounds__(TPB) void partvit_pairs(const int* __restrict__ idx,
                                                     const float* __restrict__ bh,
                                                     float* __restrict__ out) {
    const int t = blockIdx.x * blockDim.x + threadIdx.x;  // pair id = b*K + k
    if (t >= PAIRS) return;
    const int2 id = ((const int2*)idx)[t];
    const int i0 = min(max(id.x, 0), NN - 1);
    const int i1 = min(max(id.y, 0), NN - 1);
    const int b = t >> 10;  // K = 1024
    const float4 p0 = g_P[b * NN + i0];
    const float4 p1 = g_P[b * NN + i1];
    const float b0 = bh[0], b1 = bh[1];
    ((float2*)out)[t] = make_float2(p0.x + p1.z + b0, p0.y + p1.w + b1);
    ((float2*)out)[PAIRS + t] = make_float2((float)id.x, (float)id.y);
}

extern "C" void kernel_launch(void* const* d_in, const int* in_sizes, int n_in,
                              void* d_out, int out_size, void* d_ws, size_t ws_size,
                              hipStream_t stream) {
    const float* z   = (const float*)d_in[0];
    const int*   idx = (const int*)d_in[1];
    const float* W   = (const float*)d_in[2];
    const float* bh  = (const float*)d_in[3];
    float*       out = (float*)d_out;
    (void)d_ws; (void)ws_size; (void)in_sizes; (void)n_in; (void)out_size;

    // K1: 4608 blocks * 4 waves, 2 rows/wave, 8 waves/SIMD, 18 blocks/CU churn.
    partvit_proj<<<K1_BLOCKS, TPB, 0, stream>>>(z, W);
    // K2: one thread per pair.
    partvit_pairs<<<PAIRS / TPB, TPB, 0, stream>>>(idx, bh, out);
}